// Round 18
// baseline (32.726 us; speedup 1.0000x reference)
//
#include <hip/hip_runtime.h>

#define B_ 64
#define S_ 512
#define H_ 768
#define L_ 9
#define CPAD 88                 // floats per chunk record (global + LDS)

typedef __attribute__((ext_vector_type(8))) short bf16x8;
typedef __attribute__((ext_vector_type(4))) float f32x4;

// pack two fp32 -> one u32 of two bf16 (round-to-nearest via +0x8000)
__device__ __forceinline__ unsigned pack_bf16(float lo, float hi) {
    unsigned a = __float_as_uint(lo) + 0x8000u;
    unsigned b = __float_as_uint(hi) + 0x8000u;
    return __builtin_amdgcn_perm(b, a, 0x07060302);  // {b.b23, a.b23}
}

// ---------------------------------------------------------------------------
// Kernel A: block g (512 blocks, 256 thr) = 64 rows [s0, s0+64) of batch g>>3.
//   1. MFMA em = hidden@W + b (r10 core, full K) -> LDS em_t[64][12]
//   2. exp pass -> ee_t
//   3. T<36: build this block's 4 chunk transfer matrices
//      (chunk c covers t in [max(16c,1), 16c+15] -> block-aligned) -> Crec
//      T in [64,128): numerator partial (incl. start/end terms) -> num_part[g]
//      s0==0 block: raw em row 0 -> em_row0[b]
// Dead blocks (s0>=len) write num_part=0 and exit; crf substitutes identity
// for their chunks. Also zeroes out[0] (block 0, pre-CRF in stream order).
// ---------------------------------------------------------------------------
__global__ __launch_bounds__(256) void emis_kernel(
    const float* __restrict__ hidden, const float* __restrict__ W,
    const float* __restrict__ bias, const int* __restrict__ lengths,
    const int* __restrict__ labels, const float* __restrict__ start_t,
    const float* __restrict__ trans, const float* __restrict__ end_t,
    float* __restrict__ Crec, float* __restrict__ em_row0,
    float* __restrict__ num_part, float* __restrict__ out)
{
    __shared__ unsigned Wl[96 * 16 * 4];     // bf16x8 frags [k8][col], 24 KB
    __shared__ float em_t[64 * 12];          // raw em rows, 3 KB
    __shared__ float ee_t[64 * 12];          // exp(em) rows, 3 KB
    __shared__ float Pl[112];                // exp(trans), rows padded to 12
    __shared__ float bias16[16];

    const int T = threadIdx.x;
    const int g = blockIdx.x;                // 0..511
    const int b = g >> 3;
    const int s0 = (g & 7) * 64;
    if (g == 0 && T == 0) out[0] = 0.0f;
    int len = lengths[b]; if (len < 1) len = 1;
    if (s0 >= len) {                         // dead block
        if (T == 0) num_part[g] = 0.0f;
        return;
    }

    const int wv = T >> 6, lane = T & 63;
    const int q = lane >> 4, col = lane & 15;
    const int r0 = g * 64 + wv * 16;         // this wave's 16-row tile
    const bool tile_live = ((r0 & 511) < len);

    // ---- prefetch hidden for st=0..3 (starts HBM stream pre-barrier) ----
    const float* hp = hidden + (size_t)(r0 + col) * H_ + q * 8;
    float4 ph[8];
    if (tile_live) {
        #pragma unroll
        for (int st = 0; st < 4; ++st) {
            ph[2 * st]     = *(const float4*)(hp + st * 32);
            ph[2 * st + 1] = *(const float4*)(hp + st * 32 + 4);
        }
    }

    // ---- shared tables: W fragments, exp(trans), bias ----
    if (T < 16) bias16[T] = (T < 9) ? bias[T] : 0.0f;
    if (T < 81) Pl[(T / 9) * 12 + (T % 9)] = __expf(trans[T]);
    #pragma unroll
    for (int r6 = 0; r6 < 6; ++r6) {
        const int sidx = T + 256 * r6;       // 0..1535
        const int k8 = sidx >> 4, c = sidx & 15;
        unsigned w0 = 0, w1 = 0, w2 = 0, w3 = 0;
        if (c < 9) {
            const float* wp = W + (size_t)(k8 * 8) * 9 + c;
            w0 = pack_bf16(wp[0],  wp[9]);
            w1 = pack_bf16(wp[18], wp[27]);
            w2 = pack_bf16(wp[36], wp[45]);
            w3 = pack_bf16(wp[54], wp[63]);
        }
        uint4 v = { w0, w1, w2, w3 };
        *(uint4*)&Wl[sidx * 4] = v;
    }
    __syncthreads();

    // ---- MFMA: 24 steps, lane (q,col) -> em[r0+col][4q..4q+3] ----
    if (tile_live) {
        f32x4 acc = { 0.0f, 0.0f, 0.0f, 0.0f };
        #pragma unroll
        for (int st = 0; st < 24; ++st) {
            float4 h0, h1;
            if (st < 4) { h0 = ph[2 * st]; h1 = ph[2 * st + 1]; }
            else {
                h0 = *(const float4*)(hp + st * 32);
                h1 = *(const float4*)(hp + st * 32 + 4);
            }
            union { unsigned u[4]; bf16x8 v; } bu, au;
            bu.u[0] = pack_bf16(h0.x, h0.y);
            bu.u[1] = pack_bf16(h0.z, h0.w);
            bu.u[2] = pack_bf16(h1.x, h1.y);
            bu.u[3] = pack_bf16(h1.z, h1.w);
            const uint4 a4 = *(const uint4*)&Wl[((st * 4 + q) * 16 + col) * 4];
            au.u[0] = a4.x; au.u[1] = a4.y; au.u[2] = a4.z; au.u[3] = a4.w;
            acc = __builtin_amdgcn_mfma_f32_16x16x32_bf16(au.v, bu.v, acc, 0, 0, 0);
        }
        if (q < 3) {                         // cols 12..15 unused
            const float4 b4 = *(const float4*)(bias16 + q * 4);
            float4 o = { acc[0] + b4.x, acc[1] + b4.y,
                         acc[2] + b4.z, acc[3] + b4.w };
            *(float4*)&em_t[(wv * 16 + col) * 12 + q * 4] = o;
        }
    }
    __syncthreads();

    // ---- exp pass: 576 values by 192 threads ----
    if (T < 192) {
        #pragma unroll
        for (int k = 0; k < 3; ++k) {
            const int idx = T + 192 * k;     // 0..575
            const int r = idx / 9, c = idx - 9 * r;
            ee_t[r * 12 + c] = __expf(em_t[r * 12 + c]);
        }
    }
    __syncthreads();

    if (T < 36) {
        // ---- build 4 chunk matrices: chunk cg covers t in [max(16cg,1), 16cg+15]
        const int cl = T / 9, i = T - 9 * cl;
        const int cg = 4 * (g & 7) + cl;     // global chunk 0..31
        float A[9];
        #pragma unroll
        for (int j = 0; j < 9; ++j) A[j] = (i == j) ? 1.0f : 0.0f;

        #pragma unroll 1
        for (int s = 0; s < 16; ++s) {
            const int t = 16 * cg + s;
            const int r = 16 * cl + s;       // local row = t - s0
            float4 e0 = *(const float4*)&ee_t[r * 12];
            float4 e1 = *(const float4*)&ee_t[r * 12 + 4];
            const float e8 = ee_t[r * 12 + 8];
            const float e[9] = { e0.x, e0.y, e0.z, e0.w,
                                 e1.x, e1.y, e1.z, e1.w, e8 };
            float an[9];
            #pragma unroll
            for (int j = 0; j < 9; ++j) an[j] = 0.0f;
            #pragma unroll
            for (int k = 0; k < 9; ++k) {
                float4 p0 = *(const float4*)(Pl + k * 12);
                float4 p1 = *(const float4*)(Pl + k * 12 + 4);
                const float p8 = Pl[k * 12 + 8];
                const float pr[9] = { p0.x, p0.y, p0.z, p0.w,
                                      p1.x, p1.y, p1.z, p1.w, p8 };
                const float ak = A[k];
                #pragma unroll
                for (int j = 0; j < 9; ++j)
                    an[j] = fmaf(ak, pr[j], an[j]);
            }
            const bool live = (t >= 1) && (t < len);
            #pragma unroll
            for (int j = 0; j < 9; ++j)
                A[j] = live ? an[j] * e[j] : A[j];
            if (s == 7) {                    // exact 2^-40; crf adds 1280*ln2
                #pragma unroll
                for (int j = 0; j < 9; ++j) A[j] *= 0x1p-40f;
            }
        }
        float* rec = Crec + ((size_t)b * 32 + cg) * CPAD + i * 9;
        #pragma unroll
        for (int j = 0; j < 9; ++j) rec[j] = A[j];
    } else if (T >= 36 && T < 45) {
        if (s0 == 0) em_row0[b * 12 + (T - 36)] = em_t[T - 36];
    } else if (T >= 64 && T < 128) {
        // ---- numerator partial for t in [s0, s0+64) ----
        const int ln = T - 64;
        const int t = s0 + ln;
        float part = 0.0f;
        if (t >= 1 && t < len) {
            const int tp = labels[b * S_ + t - 1];
            const int tc = labels[b * S_ + t];
            part = trans[tp * 9 + tc] + em_t[ln * 12 + tc];
        }
        if (ln == 0) {
            if (s0 == 0) {
                const int l0 = labels[b * S_];
                part += start_t[l0] + em_t[l0];
            }
            if (s0 <= len - 1 && len - 1 < s0 + 64)
                part += end_t[labels[b * S_ + len - 1]];
        }
        #pragma unroll
        for (int off = 32; off >= 1; off >>= 1) part += __shfl_xor(part, off, 64);
        if (ln == 0) num_part[g] = part;
    }
}

// ---------------------------------------------------------------------------
// Kernel B (light CRF): 64 blocks x 192 threads. Load 32 chunk records
// (identity*2^-40 for dead-owner chunks), 5-level tree product, epilogue.
// ---------------------------------------------------------------------------
__global__ __launch_bounds__(192, 1) void crf_kernel(
    const float* __restrict__ Crec, const float* __restrict__ em_row0,
    const float* __restrict__ num_part, const int* __restrict__ lengths,
    const float* __restrict__ start_t, const float* __restrict__ end_t,
    float* __restrict__ out)
{
    __shared__ float Cs[32 * CPAD];          // 11 KB
    __shared__ float Cs2[16 * CPAD];
    __shared__ float rmx_s[16 * 12];
    __shared__ float lgA[32], lgB[16];
    const int T = threadIdx.x;
    const int b = blockIdx.x;
    int len = lengths[b]; if (len < 1) len = 1;

    // ---- load records (3 threads x 27 floats per chunk) ----
    if (T < 96) {
        const int c = T / 3, p = T - 3 * (T / 3);
        const bool ownerLive = ((c >> 2) * 64) < len;
        const float* rec = Crec + ((size_t)b * 32 + c) * CPAD + p * 27;
        #pragma unroll
        for (int k = 0; k < 27; ++k) {
            const int i = 3 * p + k / 9, j = k % 9;   // m = p*27+k
            Cs[c * CPAD + p * 27 + k] =
                ownerLive ? rec[k] : ((i == j) ? 0x1p-40f : 0.0f);
        }
    }
    if (T < 32) lgA[T] = 0.0f;
    __syncthreads();

    // ---- binary tree product of 32 chunk matrices (5 levels) ----
    float* src = Cs;  float* dst = Cs2;
    float* ls  = lgA; float* ld  = lgB;
    int nn = 16;
    #pragma unroll 1
    for (int lvl = 0; lvl < 5; ++lvl) {
        const int n = T / 9, i = T - 9 * n;
        float row[9];
        if (T < nn * 9) {
            const float* Am = src + (2 * n) * CPAD;
            const float* Bm = src + (2 * n + 1) * CPAD;
            float a[9];
            #pragma unroll
            for (int k = 0; k < 9; ++k) a[k] = Am[i * 9 + k];
            #pragma unroll
            for (int j = 0; j < 9; ++j) row[j] = 0.0f;
            #pragma unroll
            for (int k = 0; k < 9; ++k) {
                const float ak = a[k];
                #pragma unroll
                for (int j = 0; j < 9; ++j)
                    row[j] = fmaf(ak, Bm[k * 9 + j], row[j]);
            }
            float rmx = row[0];
            #pragma unroll
            for (int j = 1; j < 9; ++j) rmx = fmaxf(rmx, row[j]);
            rmx_s[n * 12 + i] = rmx;
        }
        __syncthreads();
        if (T < nn * 9) {
            float mx = rmx_s[n * 12];
            #pragma unroll
            for (int k = 1; k < 9; ++k) mx = fmaxf(mx, rmx_s[n * 12 + k]);
            const float inv = 1.0f / mx;
            #pragma unroll
            for (int j = 0; j < 9; ++j) dst[n * CPAD + i * 9 + j] = row[j] * inv;
            if (i == 0) ld[n] = ls[2 * n] + ls[2 * n + 1] + __logf(mx);
        }
        __syncthreads();
        float* t1 = src; src = dst; dst = t1;
        float* t2 = ls;  ls = ld;  ld = t2;
        nn >>= 1;
    }

    // ---- epilogue: alpha0, den, num, out ----
    if (T == 0) {
        float al[9];
        #pragma unroll
        for (int j = 0; j < 9; ++j) al[j] = em_row0[b * 12 + j] + start_t[j];
        float m0 = al[0];
        #pragma unroll
        for (int j = 1; j < 9; ++j) m0 = fmaxf(m0, al[j]);
        float alpha[9];
        #pragma unroll
        for (int j = 0; j < 9; ++j) alpha[j] = __expf(al[j] - m0);

        float ev = 0.0f;
        #pragma unroll
        for (int j = 0; j < 9; ++j) {
            float s = 0.0f;
            #pragma unroll
            for (int i = 0; i < 9; ++i)
                s = fmaf(alpha[i], src[i * 9 + j], s);
            ev = fmaf(s, __expf(end_t[j]), ev);
        }
        const float den = m0 + ls[0] + __logf(ev)
                        + 1280.0f * 0.6931471805599453f;   // 32 x 2^-40
        float num = 0.0f;
        #pragma unroll
        for (int k = 0; k < 8; ++k) num += num_part[b * 8 + k];
        atomicAdd(out, den - num);
    }
}

// ---------------------------------------------------------------------------
extern "C" void kernel_launch(void* const* d_in, const int* in_sizes, int n_in,
                              void* d_out, int out_size, void* d_ws, size_t ws_size,
                              hipStream_t stream)
{
    (void)in_sizes; (void)n_in; (void)out_size; (void)ws_size;
    const float* hidden  = (const float*)d_in[0];
    const float* W       = (const float*)d_in[1];
    const float* bias    = (const float*)d_in[2];
    const float* start_t = (const float*)d_in[3];
    const float* trans   = (const float*)d_in[4];
    const float* end_t   = (const float*)d_in[5];
    const int*   labels  = (const int*)d_in[6];
    const int*   lengths = (const int*)d_in[7];

    float* Crec     = (float*)d_ws;                     // 64*32*88 floats
    float* em_row0  = Crec + (size_t)64 * 32 * CPAD;    // 64*12
    float* num_part = em_row0 + 64 * 12;                // 512
    float* out      = (float*)d_out;

    emis_kernel<<<512, 256, 0, stream>>>(hidden, W, bias, lengths, labels,
                                         start_t, trans, end_t,
                                         Crec, em_row0, num_part, out);
    crf_kernel<<<B_, 192, 0, stream>>>(Crec, em_row0, num_part, lengths,
                                       start_t, end_t, out);
}

// Round 19
// 32.479 us; speedup vs baseline: 1.0076x; 1.0076x over previous
//
#include <hip/hip_runtime.h>

#define B_ 64
#define S_ 512
#define H_ 768
#define L_ 9
#define CPAD 88                 // floats per chunk record (global + LDS)

typedef __attribute__((ext_vector_type(8))) short bf16x8;
typedef __attribute__((ext_vector_type(4))) float f32x4;

// pack two fp32 -> one u32 of two bf16 (round-to-nearest via +0x8000)
__device__ __forceinline__ unsigned pack_bf16(float lo, float hi) {
    unsigned a = __float_as_uint(lo) + 0x8000u;
    unsigned b = __float_as_uint(hi) + 0x8000u;
    return __builtin_amdgcn_perm(b, a, 0x07060302);  // {b.b23, a.b23}
}

// ---------------------------------------------------------------------------
// Kernel A: block g (512 blocks, 256 thr) = 64 rows [s0, s0+64) of batch g>>3.
//   1. MFMA em = hidden@W + b (r10 core, full K) -> LDS em_t[64][12]
//   2. exp pass -> ee_t
//   3. T<36: build this block's 4 chunk transfer matrices
//      (chunk c covers t in [max(16c,1), 16c+15] -> block-aligned) -> Crec
//      T in [64,128): numerator partial (incl. start/end terms) -> num_part[g]
//      s0==0 block: raw em row 0 -> em_row0[b]
// Dead blocks (s0>=len) write num_part=0 and exit; crf substitutes identity
// for their chunks. Also zeroes out[0] (block 0, pre-CRF in stream order).
// ---------------------------------------------------------------------------
__global__ __launch_bounds__(256) void emis_kernel(
    const float* __restrict__ hidden, const float* __restrict__ W,
    const float* __restrict__ bias, const int* __restrict__ lengths,
    const int* __restrict__ labels, const float* __restrict__ start_t,
    const float* __restrict__ trans, const float* __restrict__ end_t,
    float* __restrict__ Crec, float* __restrict__ em_row0,
    float* __restrict__ num_part, float* __restrict__ out)
{
    __shared__ unsigned Wl[96 * 16 * 4];     // bf16x8 frags [k8][col], 24 KB
    __shared__ float em_t[64 * 12];          // raw em rows, 3 KB
    __shared__ float ee_t[64 * 12];          // exp(em) rows, 3 KB
    __shared__ float Pl[112];                // exp(trans), rows padded to 12
    __shared__ float bias16[16];

    const int T = threadIdx.x;
    const int g = blockIdx.x;                // 0..511
    const int b = g >> 3;
    const int s0 = (g & 7) * 64;
    if (g == 0 && T == 0) out[0] = 0.0f;
    int len = lengths[b]; if (len < 1) len = 1;
    if (s0 >= len) {                         // dead block
        if (T == 0) num_part[g] = 0.0f;
        return;
    }

    const int wv = T >> 6, lane = T & 63;
    const int q = lane >> 4, col = lane & 15;
    const int r0 = g * 64 + wv * 16;         // this wave's 16-row tile
    const bool tile_live = ((r0 & 511) < len);

    // ---- prefetch hidden for st=0..3 (starts HBM stream pre-barrier) ----
    const float* hp = hidden + (size_t)(r0 + col) * H_ + q * 8;
    float4 ph[8];
    if (tile_live) {
        #pragma unroll
        for (int st = 0; st < 4; ++st) {
            ph[2 * st]     = *(const float4*)(hp + st * 32);
            ph[2 * st + 1] = *(const float4*)(hp + st * 32 + 4);
        }
    }

    // ---- shared tables: W fragments, exp(trans), bias ----
    if (T < 16) bias16[T] = (T < 9) ? bias[T] : 0.0f;
    if (T < 81) Pl[(T / 9) * 12 + (T % 9)] = __expf(trans[T]);
    #pragma unroll
    for (int r6 = 0; r6 < 6; ++r6) {
        const int sidx = T + 256 * r6;       // 0..1535
        const int k8 = sidx >> 4, c = sidx & 15;
        unsigned w0 = 0, w1 = 0, w2 = 0, w3 = 0;
        if (c < 9) {
            const float* wp = W + (size_t)(k8 * 8) * 9 + c;
            w0 = pack_bf16(wp[0],  wp[9]);
            w1 = pack_bf16(wp[18], wp[27]);
            w2 = pack_bf16(wp[36], wp[45]);
            w3 = pack_bf16(wp[54], wp[63]);
        }
        uint4 v = { w0, w1, w2, w3 };
        *(uint4*)&Wl[sidx * 4] = v;
    }
    __syncthreads();

    // ---- MFMA: 24 steps, lane (q,col) -> em[r0+col][4q..4q+3] ----
    if (tile_live) {
        f32x4 acc = { 0.0f, 0.0f, 0.0f, 0.0f };
        #pragma unroll
        for (int st = 0; st < 24; ++st) {
            float4 h0, h1;
            if (st < 4) { h0 = ph[2 * st]; h1 = ph[2 * st + 1]; }
            else {
                h0 = *(const float4*)(hp + st * 32);
                h1 = *(const float4*)(hp + st * 32 + 4);
            }
            union { unsigned u[4]; bf16x8 v; } bu, au;
            bu.u[0] = pack_bf16(h0.x, h0.y);
            bu.u[1] = pack_bf16(h0.z, h0.w);
            bu.u[2] = pack_bf16(h1.x, h1.y);
            bu.u[3] = pack_bf16(h1.z, h1.w);
            const uint4 a4 = *(const uint4*)&Wl[((st * 4 + q) * 16 + col) * 4];
            au.u[0] = a4.x; au.u[1] = a4.y; au.u[2] = a4.z; au.u[3] = a4.w;
            acc = __builtin_amdgcn_mfma_f32_16x16x32_bf16(au.v, bu.v, acc, 0, 0, 0);
        }
        if (q < 3) {                         // cols 12..15 unused
            const float4 b4 = *(const float4*)(bias16 + q * 4);
            float4 o = { acc[0] + b4.x, acc[1] + b4.y,
                         acc[2] + b4.z, acc[3] + b4.w };
            *(float4*)&em_t[(wv * 16 + col) * 12 + q * 4] = o;
        }
    }
    __syncthreads();

    // ---- exp pass: 576 values by 192 threads ----
    if (T < 192) {
        #pragma unroll
        for (int k = 0; k < 3; ++k) {
            const int idx = T + 192 * k;     // 0..575
            const int r = idx / 9, c = idx - 9 * r;
            ee_t[r * 12 + c] = __expf(em_t[r * 12 + c]);
        }
    }
    __syncthreads();

    if (T < 36) {
        // ---- build 4 chunk matrices: chunk cg covers t in [max(16cg,1), 16cg+15]
        const int cl = T / 9, i = T - 9 * cl;
        const int cg = 4 * (g & 7) + cl;     // global chunk 0..31
        float A[9];
        #pragma unroll
        for (int j = 0; j < 9; ++j) A[j] = (i == j) ? 1.0f : 0.0f;

        #pragma unroll 1
        for (int s = 0; s < 16; ++s) {
            const int t = 16 * cg + s;
            const int r = 16 * cl + s;       // local row = t - s0
            float4 e0 = *(const float4*)&ee_t[r * 12];
            float4 e1 = *(const float4*)&ee_t[r * 12 + 4];
            const float e8 = ee_t[r * 12 + 8];
            const float e[9] = { e0.x, e0.y, e0.z, e0.w,
                                 e1.x, e1.y, e1.z, e1.w, e8 };
            float an[9];
            #pragma unroll
            for (int j = 0; j < 9; ++j) an[j] = 0.0f;
            #pragma unroll
            for (int k = 0; k < 9; ++k) {
                float4 p0 = *(const float4*)(Pl + k * 12);
                float4 p1 = *(const float4*)(Pl + k * 12 + 4);
                const float p8 = Pl[k * 12 + 8];
                const float pr[9] = { p0.x, p0.y, p0.z, p0.w,
                                      p1.x, p1.y, p1.z, p1.w, p8 };
                const float ak = A[k];
                #pragma unroll
                for (int j = 0; j < 9; ++j)
                    an[j] = fmaf(ak, pr[j], an[j]);
            }
            const bool live = (t >= 1) && (t < len);
            #pragma unroll
            for (int j = 0; j < 9; ++j)
                A[j] = live ? an[j] * e[j] : A[j];
            if (s == 7) {                    // exact 2^-40; crf adds 1280*ln2
                #pragma unroll
                for (int j = 0; j < 9; ++j) A[j] *= 0x1p-40f;
            }
        }
        float* rec = Crec + ((size_t)b * 32 + cg) * CPAD + i * 9;
        #pragma unroll
        for (int j = 0; j < 9; ++j) rec[j] = A[j];
    } else if (T >= 36 && T < 45) {
        if (s0 == 0) em_row0[b * 12 + (T - 36)] = em_t[T - 36];
    } else if (T >= 64 && T < 128) {
        // ---- numerator partial for t in [s0, s0+64) ----
        const int ln = T - 64;
        const int t = s0 + ln;
        float part = 0.0f;
        if (t >= 1 && t < len) {
            const int tp = labels[b * S_ + t - 1];
            const int tc = labels[b * S_ + t];
            part = trans[tp * 9 + tc] + em_t[ln * 12 + tc];
        }
        if (ln == 0) {
            if (s0 == 0) {
                const int l0 = labels[b * S_];
                part += start_t[l0] + em_t[l0];
            }
            if (s0 <= len - 1 && len - 1 < s0 + 64)
                part += end_t[labels[b * S_ + len - 1]];
        }
        #pragma unroll
        for (int off = 32; off >= 1; off >>= 1) part += __shfl_xor(part, off, 64);
        if (ln == 0) num_part[g] = part;
    }
}

// ---------------------------------------------------------------------------
// Kernel B (light CRF): 64 blocks x 192 threads. Load 32 chunk records
// (identity*2^-40 for dead-owner chunks), 5-level tree product, epilogue.
// ---------------------------------------------------------------------------
__global__ __launch_bounds__(192, 1) void crf_kernel(
    const float* __restrict__ Crec, const float* __restrict__ em_row0,
    const float* __restrict__ num_part, const int* __restrict__ lengths,
    const float* __restrict__ start_t, const float* __restrict__ end_t,
    float* __restrict__ out)
{
    __shared__ float Cs[32 * CPAD];          // 11 KB
    __shared__ float Cs2[16 * CPAD];
    __shared__ float rmx_s[16 * 12];
    __shared__ float lgA[32], lgB[16];
    const int T = threadIdx.x;
    const int b = blockIdx.x;
    int len = lengths[b]; if (len < 1) len = 1;

    // ---- load records (3 threads x 27 floats per chunk) ----
    if (T < 96) {
        const int c = T / 3, p = T - 3 * (T / 3);
        const bool ownerLive = ((c >> 2) * 64) < len;
        const float* rec = Crec + ((size_t)b * 32 + c) * CPAD + p * 27;
        #pragma unroll
        for (int k = 0; k < 27; ++k) {
            const int i = 3 * p + k / 9, j = k % 9;   // m = p*27+k
            Cs[c * CPAD + p * 27 + k] =
                ownerLive ? rec[k] : ((i == j) ? 0x1p-40f : 0.0f);
        }
    }
    if (T < 32) lgA[T] = 0.0f;
    __syncthreads();

    // ---- binary tree product of 32 chunk matrices (5 levels) ----
    float* src = Cs;  float* dst = Cs2;
    float* ls  = lgA; float* ld  = lgB;
    int nn = 16;
    #pragma unroll 1
    for (int lvl = 0; lvl < 5; ++lvl) {
        const int n = T / 9, i = T - 9 * n;
        float row[9];
        if (T < nn * 9) {
            const float* Am = src + (2 * n) * CPAD;
            const float* Bm = src + (2 * n + 1) * CPAD;
            float a[9];
            #pragma unroll
            for (int k = 0; k < 9; ++k) a[k] = Am[i * 9 + k];
            #pragma unroll
            for (int j = 0; j < 9; ++j) row[j] = 0.0f;
            #pragma unroll
            for (int k = 0; k < 9; ++k) {
                const float ak = a[k];
                #pragma unroll
                for (int j = 0; j < 9; ++j)
                    row[j] = fmaf(ak, Bm[k * 9 + j], row[j]);
            }
            float rmx = row[0];
            #pragma unroll
            for (int j = 1; j < 9; ++j) rmx = fmaxf(rmx, row[j]);
            rmx_s[n * 12 + i] = rmx;
        }
        __syncthreads();
        if (T < nn * 9) {
            float mx = rmx_s[n * 12];
            #pragma unroll
            for (int k = 1; k < 9; ++k) mx = fmaxf(mx, rmx_s[n * 12 + k]);
            const float inv = 1.0f / mx;
            #pragma unroll
            for (int j = 0; j < 9; ++j) dst[n * CPAD + i * 9 + j] = row[j] * inv;
            if (i == 0) ld[n] = ls[2 * n] + ls[2 * n + 1] + __logf(mx);
        }
        __syncthreads();
        float* t1 = src; src = dst; dst = t1;
        float* t2 = ls;  ls = ld;  ld = t2;
        nn >>= 1;
    }

    // ---- epilogue: alpha0, den, num, out ----
    if (T == 0) {
        float al[9];
        #pragma unroll
        for (int j = 0; j < 9; ++j) al[j] = em_row0[b * 12 + j] + start_t[j];
        float m0 = al[0];
        #pragma unroll
        for (int j = 1; j < 9; ++j) m0 = fmaxf(m0, al[j]);
        float alpha[9];
        #pragma unroll
        for (int j = 0; j < 9; ++j) alpha[j] = __expf(al[j] - m0);

        float ev = 0.0f;
        #pragma unroll
        for (int j = 0; j < 9; ++j) {
            float s = 0.0f;
            #pragma unroll
            for (int i = 0; i < 9; ++i)
                s = fmaf(alpha[i], src[i * 9 + j], s);
            ev = fmaf(s, __expf(end_t[j]), ev);
        }
        const float den = m0 + ls[0] + __logf(ev)
                        + 1280.0f * 0.6931471805599453f;   // 32 x 2^-40
        float num = 0.0f;
        #pragma unroll
        for (int k = 0; k < 8; ++k) num += num_part[b * 8 + k];
        atomicAdd(out, den - num);
    }
}

// ---------------------------------------------------------------------------
extern "C" void kernel_launch(void* const* d_in, const int* in_sizes, int n_in,
                              void* d_out, int out_size, void* d_ws, size_t ws_size,
                              hipStream_t stream)
{
    (void)in_sizes; (void)n_in; (void)out_size; (void)ws_size;
    const float* hidden  = (const float*)d_in[0];
    const float* W       = (const float*)d_in[1];
    const float* bias    = (const float*)d_in[2];
    const float* start_t = (const float*)d_in[3];
    const float* trans   = (const float*)d_in[4];
    const float* end_t   = (const float*)d_in[5];
    const int*   labels  = (const int*)d_in[6];
    const int*   lengths = (const int*)d_in[7];

    float* Crec     = (float*)d_ws;                     // 64*32*88 floats
    float* em_row0  = Crec + (size_t)64 * 32 * CPAD;    // 64*12
    float* num_part = em_row0 + 64 * 12;                // 512
    float* out      = (float*)d_out;

    emis_kernel<<<512, 256, 0, stream>>>(hidden, W, bias, lengths, labels,
                                         start_t, trans, end_t,
                                         Crec, em_row0, num_part, out);
    crf_kernel<<<B_, 192, 0, stream>>>(Crec, em_row0, num_part, lengths,
                                       start_t, end_t, out);
}

// Round 20
// 31.466 us; speedup vs baseline: 1.0401x; 1.0322x over previous
//
#include <hip/hip_runtime.h>

#define B_ 64
#define S_ 512
#define H_ 768
#define L_ 9
#define EMP 16                  // padded emission row stride in global (floats)
#define CH 16                   // timesteps per chunk
#define NCHUNK 32               // chunks per batch
#define CPAD 88                 // floats per chunk record in LDS (16B-aligned)

typedef __attribute__((ext_vector_type(8))) short bf16x8;
typedef __attribute__((ext_vector_type(4))) float f32x4;
typedef bf16x8 __attribute__((may_alias)) bf16x8_a;
typedef uint2  __attribute__((may_alias)) uint2_a;

// eem LDS offset for timestep t: 16B-aligned, bank-staggered per 16-row group
__device__ __forceinline__ int eoff(int t) { return t * 12 + (t >> 4) * 4; }

// pack two fp32 -> one u32 of two bf16 (round-to-nearest via +0x8000)
__device__ __forceinline__ unsigned pack_bf16(float lo, float hi) {
    unsigned a = __float_as_uint(lo) + 0x8000u;
    unsigned b = __float_as_uint(hi) + 0x8000u;
    return __builtin_amdgcn_perm(b, a, 0x07060302);  // {b.b23, a.b23}
}

// ---------------------------------------------------------------------------
// Kernel A (MFMA, coalesced-staged): em[b][s][16] = hidden @ W + b.
// Block = 64 rows (4 waves x 16-row tile), 512 blocks. r10 skeleton, but the
// hidden stream goes global->reg(COALESCED: each load = 16 fully-used 64B
// sectors, lane l>>2=row, (l&3)*16=offset)->bf16 pack->per-wave LDS panel
// (double-buffered, 144B padded rows = conflict-free)->ds_read_b128 fragments.
// Prior variants' per-lane strided loads touched 32 HALF-used sectors/instr.
// Same wave stages and consumes: no barriers in the K loop.
// Also zeroes out[0] (runs before the CRF kernel in stream order).
// ---------------------------------------------------------------------------
__global__ __launch_bounds__(256) void emis_kernel(
    const float* __restrict__ hidden, const float* __restrict__ W,
    const float* __restrict__ bias, const int* __restrict__ lengths,
    float* __restrict__ em, float* __restrict__ out)
{
    __shared__ unsigned Wl[96 * 16 * 4];     // bf16x8 frags [k8][col] (24 KB)
    __shared__ float bias16[16];
    __shared__ unsigned hbuf[4][2][16 * 36]; // per-wave panels: 16 rows x 144B

    const int T = threadIdx.x;
    if (blockIdx.x == 0 && T == 0) out[0] = 0.0f;

    const int g = blockIdx.x;                // 64-row group
    const int b = g >> 3;
    int len = lengths[b]; if (len < 1) len = 1;
    if (((g & 7) * 64) >= len) return;       // whole block masked

    const int wv = T >> 6, lane = T & 63;
    const int q = lane >> 4, col = lane & 15;
    const int r0 = g * 64 + wv * 16;         // this wave's 16-row tile
    const bool tile_live = ((r0 & 511) < len);

    // stager mapping: lane -> (row l>>2, 16B at (l&3)*16 of each 64B run)
    const int srow = lane >> 2, sm = lane & 3;
    const float* hrow = hidden + (size_t)(r0 + srow) * H_ + sm * 4;

    // ---- prefetch panels 0,1 (coalesced; starts HBM stream pre-barrier) ----
    float4 L[2][4];
    if (tile_live) {
        #pragma unroll
        for (int m = 0; m < 4; ++m) L[0][m] = *(const float4*)(hrow + m * 16);
        #pragma unroll
        for (int m = 0; m < 4; ++m) L[1][m] = *(const float4*)(hrow + 64 + m * 16);
    }

    // ---- pack W fragments from global W (L1/L2-resident) ----
    if (T < 16) bias16[T] = (T < 9) ? bias[T] : 0.0f;
    #pragma unroll
    for (int r6 = 0; r6 < 6; ++r6) {
        const int sidx = T + 256 * r6;       // 0..1535
        const int k8 = sidx >> 4, c = sidx & 15;
        unsigned w0 = 0, w1 = 0, w2 = 0, w3 = 0;
        if (c < 9) {
            const float* wp = W + (size_t)(k8 * 8) * 9 + c;
            w0 = pack_bf16(wp[0],  wp[9]);
            w1 = pack_bf16(wp[18], wp[27]);
            w2 = pack_bf16(wp[36], wp[45]);
            w3 = pack_bf16(wp[54], wp[63]);
        }
        uint4 v = { w0, w1, w2, w3 };
        *(uint4*)&Wl[sidx * 4] = v;
    }
    __syncthreads();

    if (!tile_live) return;

    unsigned* buf0 = &hbuf[wv][0][0];
    unsigned* buf1 = &hbuf[wv][1][0];
    const int woff = srow * 36 + sm * 2;     // u32 write offset (+ m*8)
    const int rdoff = col * 36 + q * 4;      // u32 read offset (+ s*16)

    // write panel 0
    #pragma unroll
    for (int m = 0; m < 4; ++m) {
        uint2 u = { pack_bf16(L[0][m].x, L[0][m].y),
                    pack_bf16(L[0][m].z, L[0][m].w) };
        *(uint2_a*)(buf0 + woff + m * 8) = u;
    }

    const float4 bias4 = *(const float4*)(bias16 + q * 4);
    f32x4 acc = { 0.0f, 0.0f, 0.0f, 0.0f };

    #pragma unroll
    for (int p = 0; p < 12; ++p) {
        unsigned* cbuf = (p & 1) ? buf1 : buf0;
        unsigned* nbuf = (p & 1) ? buf0 : buf1;

        // prefetch panel p+2 into L[p&1] (its panel p already in LDS)
        if (p + 2 < 12) {
            #pragma unroll
            for (int m = 0; m < 4; ++m)
                L[p & 1][m] = *(const float4*)(hrow + (p + 2) * 64 + m * 16);
        }

        // consume panel p: 2 MFMA steps
        #pragma unroll
        for (int s = 0; s < 2; ++s) {
            const bf16x8 bu = *(const bf16x8_a*)(cbuf + rdoff + s * 16);
            const uint4 a4 =
                *(const uint4*)&Wl[(((p * 2 + s) * 4 + q) * 16 + col) * 4];
            union { unsigned u[4]; bf16x8 v; } au;
            au.u[0] = a4.x; au.u[1] = a4.y; au.u[2] = a4.z; au.u[3] = a4.w;
            acc = __builtin_amdgcn_mfma_f32_16x16x32_bf16(au.v, bu, acc, 0, 0, 0);
        }

        // write panel p+1
        if (p + 1 < 12) {
            #pragma unroll
            for (int m = 0; m < 4; ++m) {
                uint2 u = { pack_bf16(L[(p + 1) & 1][m].x, L[(p + 1) & 1][m].y),
                            pack_bf16(L[(p + 1) & 1][m].z, L[(p + 1) & 1][m].w) };
                *(uint2_a*)(nbuf + woff + m * 8) = u;
            }
        }
    }

    const int srow_out = (r0 & 511) + col;
    if (srow_out < len) {
        float4 o = { acc[0] + bias4.x, acc[1] + bias4.y,
                     acc[2] + bias4.z, acc[3] + bias4.w };
        *(float4*)(em + (size_t)((b << 9) + srow_out) * EMP + q * 4) = o;
    }
}

// ---------------------------------------------------------------------------
// Kernel B (fused CRF): one block per batch, 384 threads.  (r10's crf)
//  phase 0: Pl=exp(trans) -> LDS; eem=exp(em) -> LDS for t<len only.
//  phase 1: T<288: build 32 chunk transfer matrices (1 chunk/thread, row i);
//           T>=320: gold-path numerator.
//  phase 2: binary tree product of the 32 matrices (5 levels, adaptive
//           rescale, logs in LDS), then thread 0 applies alpha0 and end_t.
// ---------------------------------------------------------------------------
__global__ __launch_bounds__(384, 1) void crf_kernel(
    const float* __restrict__ em, const int* __restrict__ labels,
    const int* __restrict__ lengths, const float* __restrict__ start_t,
    const float* __restrict__ trans, const float* __restrict__ end_t,
    float* __restrict__ out)
{
    __shared__ float eem[6288];              // staggered exp(em) rows, 24.6 KiB
    __shared__ float Pl[112];                // exp(trans), rows padded to 12
    __shared__ float Cs[NCHUNK * CPAD];      // chunk matrices, 11 KiB
    __shared__ float Cs2[16 * CPAD];         // tree ping-pong, 5.5 KiB
    __shared__ float rmx_s[16 * 12];
    __shared__ float lgA[32], lgB[16];
    const int T = threadIdx.x;
    const int b = blockIdx.x;
    int len = lengths[b]; if (len < 1) len = 1;

    // ---- phase 0: shared tables ----
    if (T < 81) {
        const int k = T / 9, j = T - 9 * k;
        Pl[k * 12 + j] = __expf(trans[T]);
    }
    #pragma unroll
    for (int r = 0; r < 2; ++r) {
        const int t = T + 384 * r;
        if (t < len) {                       // rows >= len are never used
            const int o = eoff(t);
            const float4* p = (const float4*)(em + (size_t)((b << 9) + t) * EMP);
            float4 v0 = p[0], v1 = p[1], v2 = p[2];
            float4 w0 = { __expf(v0.x), __expf(v0.y), __expf(v0.z), __expf(v0.w) };
            float4 w1 = { __expf(v1.x), __expf(v1.y), __expf(v1.z), __expf(v1.w) };
            *(float4*)(eem + o) = w0;
            *(float4*)(eem + o + 4) = w1;
            eem[o + 8] = __expf(v2.x);
        }
    }
    if (T < 32) lgA[T] = 0.0f;
    __syncthreads();

    // ---- phase 1 ----
    if (T < 288) {
        const int c = T / 9;                 // 0..31, one chunk per thread
        const int i = T - 9 * c;
        float A[9];
        #pragma unroll
        for (int j = 0; j < 9; ++j) A[j] = (i == j) ? 1.0f : 0.0f;
        const int t0 = CH * c + 1;

        #pragma unroll 1
        for (int s = 0; s < CH; ++s) {
            const int t = t0 + s;
            const int o = eoff(t);
            float4 e0 = *(const float4*)(eem + o);
            float4 e1 = *(const float4*)(eem + o + 4);
            const float e8 = eem[o + 8];
            const float e[9] = { e0.x, e0.y, e0.z, e0.w,
                                 e1.x, e1.y, e1.z, e1.w, e8 };

            float an[9];
            #pragma unroll
            for (int j = 0; j < 9; ++j) an[j] = 0.0f;
            #pragma unroll
            for (int k = 0; k < 9; ++k) {
                float4 p0 = *(const float4*)(Pl + k * 12);
                float4 p1 = *(const float4*)(Pl + k * 12 + 4);
                const float p8 = Pl[k * 12 + 8];
                const float pr[9] = { p0.x, p0.y, p0.z, p0.w,
                                      p1.x, p1.y, p1.z, p1.w, p8 };
                const float ak = A[k];
                #pragma unroll
                for (int j = 0; j < 9; ++j)
                    an[j] = fmaf(ak, pr[j], an[j]);
            }
            const bool live = (t < len);
            #pragma unroll
            for (int j = 0; j < 9; ++j)
                A[j] = live ? an[j] * e[j] : A[j];
            if (s == 7) {                    // exact 2^-40; constant added at end
                #pragma unroll
                for (int j = 0; j < 9; ++j) A[j] *= 0x1p-40f;
            }
        }
        #pragma unroll
        for (int j = 0; j < 9; ++j) Cs[c * CPAD + i * 9 + j] = A[j];
    } else if (T >= 320) {
        // ---- numerator ----
        const int lane = T - 320;
        const int* lab = labels + (size_t)b * S_;
        float part = 0.0f;
        for (int t = 1 + lane; t < len; t += 64) {
            const int tp = lab[t - 1], tc = lab[t];
            part += trans[tp * 9 + tc] + em[(size_t)((b << 9) + t) * EMP + tc];
        }
        #pragma unroll
        for (int off = 32; off >= 1; off >>= 1) part += __shfl_xor(part, off, 64);
        if (lane == 0) {
            const int l0 = lab[0], le = lab[len - 1];
            const float num = start_t[l0] + em[(size_t)(b << 9) * EMP + l0]
                            + part + end_t[le];
            atomicAdd(out, -num);
        }
    }
    __syncthreads();

    // ---- phase 2a: binary tree product of 32 chunk matrices (5 levels) ----
    float* src = Cs;  float* dst = Cs2;
    float* ls  = lgA; float* ld  = lgB;
    int nn = 16;                             // output nodes this level
    #pragma unroll 1
    for (int lvl = 0; lvl < 5; ++lvl) {
        const int n = T / 9, i = T - 9 * n;
        float row[9];
        if (T < nn * 9) {
            const float* Am = src + (2 * n) * CPAD;
            const float* Bm = src + (2 * n + 1) * CPAD;
            float a[9];
            #pragma unroll
            for (int k = 0; k < 9; ++k) a[k] = Am[i * 9 + k];
            #pragma unroll
            for (int j = 0; j < 9; ++j) row[j] = 0.0f;
            #pragma unroll
            for (int k = 0; k < 9; ++k) {
                const float ak = a[k];
                #pragma unroll
                for (int j = 0; j < 9; ++j)
                    row[j] = fmaf(ak, Bm[k * 9 + j], row[j]);
            }
            float rmx = row[0];
            #pragma unroll
            for (int j = 1; j < 9; ++j) rmx = fmaxf(rmx, row[j]);
            rmx_s[n * 12 + i] = rmx;
        }
        __syncthreads();
        if (T < nn * 9) {
            float mx = rmx_s[n * 12];
            #pragma unroll
            for (int k = 1; k < 9; ++k) mx = fmaxf(mx, rmx_s[n * 12 + k]);
            const float inv = 1.0f / mx;
            #pragma unroll
            for (int j = 0; j < 9; ++j) dst[n * CPAD + i * 9 + j] = row[j] * inv;
            if (i == 0) ld[n] = ls[2 * n] + ls[2 * n + 1] + __logf(mx);
        }
        __syncthreads();
        float* t1 = src; src = dst; dst = t1;
        float* t2 = ls;  ls = ld;  ld = t2;
        nn >>= 1;
    }
    // src = final normalized matrix (node 0), ls[0] = accumulated log

    // ---- phase 2b: apply alpha0 and end transitions ----
    if (T == 0) {
        const float4* e0 = (const float4*)(em + (size_t)(b << 9) * EMP);
        float4 v0 = e0[0], v1 = e0[1], v2 = e0[2];
        float al[9] = { v0.x + start_t[0], v0.y + start_t[1], v0.z + start_t[2],
                        v0.w + start_t[3], v1.x + start_t[4], v1.y + start_t[5],
                        v1.z + start_t[6], v1.w + start_t[7], v2.x + start_t[8] };
        float m0 = al[0];
        #pragma unroll
        for (int j = 1; j < 9; ++j) m0 = fmaxf(m0, al[j]);
        float alpha[9];
        #pragma unroll
        for (int j = 0; j < 9; ++j) alpha[j] = __expf(al[j] - m0);

        float ev = 0.0f;
        #pragma unroll
        for (int j = 0; j < 9; ++j) {
            float s = 0.0f;
            #pragma unroll
            for (int i = 0; i < 9; ++i)
                s = fmaf(alpha[i], src[i * 9 + j], s);
            ev = fmaf(s, __expf(end_t[j]), ev);
        }
        // 32 chunks x 2^-40 scaling -> +1280*ln2 exact constant
        const float den = m0 + ls[0] + __logf(ev)
                        + 1280.0f * 0.6931471805599453f;
        atomicAdd(out, den);
    }
}

// ---------------------------------------------------------------------------
extern "C" void kernel_launch(void* const* d_in, const int* in_sizes, int n_in,
                              void* d_out, int out_size, void* d_ws, size_t ws_size,
                              hipStream_t stream)
{
    (void)in_sizes; (void)n_in; (void)out_size; (void)ws_size;
    const float* hidden  = (const float*)d_in[0];
    const float* W       = (const float*)d_in[1];
    const float* bias    = (const float*)d_in[2];
    const float* start_t = (const float*)d_in[3];
    const float* trans   = (const float*)d_in[4];
    const float* end_t   = (const float*)d_in[5];
    const int*   labels  = (const int*)d_in[6];
    const int*   lengths = (const int*)d_in[7];

    float* em  = (float*)d_ws;               // 64*512*16 floats = 2 MB
    float* out = (float*)d_out;

    emis_kernel<<<512, 256, 0, stream>>>(hidden, W, bias, lengths, em, out);
    crf_kernel<<<B_, 384, 0, stream>>>(em, labels, lengths,
                                       start_t, trans, end_t, out);
}

// Round 21
// 29.298 us; speedup vs baseline: 1.1170x; 1.0740x over previous
//
#include <hip/hip_runtime.h>

#define B_ 64
#define S_ 512
#define H_ 768
#define L_ 9
#define EMP 16                  // padded emission row stride in global (floats)
#define CH 16                   // timesteps per chunk
#define NCHUNK 32               // chunks per batch
#define CPAD 88                 // floats per chunk record in LDS (16B-aligned)

typedef __attribute__((ext_vector_type(8))) short bf16x8;
typedef __attribute__((ext_vector_type(4))) float f32x4;
typedef bf16x8 __attribute__((may_alias)) bf16x8_a;
typedef uint2  __attribute__((may_alias)) uint2_a;

// eem LDS offset for timestep t: 16B-aligned, bank-staggered per 16-row group
__device__ __forceinline__ int eoff(int t) { return t * 12 + (t >> 4) * 4; }

// pack two fp32 -> one u32 of two bf16 (round-to-nearest via +0x8000)
__device__ __forceinline__ unsigned pack_bf16(float lo, float hi) {
    unsigned a = __float_as_uint(lo) + 0x8000u;
    unsigned b = __float_as_uint(hi) + 0x8000u;
    return __builtin_amdgcn_perm(b, a, 0x07060302);  // {b.b23, a.b23}
}

// ---------------------------------------------------------------------------
// Kernel A (MFMA, coalesced-staged, SCATTERED tiles): em = hidden @ W + b.
// 2048 16-row tiles flattened; wave w of block g takes tile g + 512*w
// (r20 took 4g+w). Liveness is contiguous in tile space (variable lengths),
// so contiguous assignment quantizes per-CU work to 8us block granules;
// scattering makes per-block live work ~uniform (worst-CU bytes 384->~250KB).
// Hidden stream: coalesced global->reg->bf16 pack->per-wave LDS panel
// (double-buffered, 144B rows)->ds_read_b128 fragments; no K-loop barriers.
// Also zeroes out[0] (runs before the CRF kernel in stream order).
// ---------------------------------------------------------------------------
__global__ __launch_bounds__(256) void emis_kernel(
    const float* __restrict__ hidden, const float* __restrict__ W,
    const float* __restrict__ bias, const int* __restrict__ lengths,
    float* __restrict__ em, float* __restrict__ out)
{
    __shared__ unsigned Wl[96 * 16 * 4];     // bf16x8 frags [k8][col] (24 KB)
    __shared__ float bias16[16];
    __shared__ unsigned hbuf[4][2][16 * 36]; // per-wave panels: 16 rows x 144B

    const int T = threadIdx.x;
    if (blockIdx.x == 0 && T == 0) out[0] = 0.0f;

    const int g = blockIdx.x;                // 0..511

    // all-4-tiles-dead early exit (uniform; ~4% of blocks)
    int live_any = 0;
    #pragma unroll
    for (int w = 0; w < 4; ++w) {
        const int ttw = g + 512 * w;
        int lw = lengths[ttw >> 5]; if (lw < 1) lw = 1;
        if (((ttw & 31) * 16) < lw) live_any = 1;
    }
    if (!live_any) return;

    const int wv = T >> 6, lane = T & 63;
    const int q = lane >> 4, col = lane & 15;

    const int tt = g + 512 * wv;             // this wave's tile, 0..2047
    const int b  = tt >> 5;                  // batch
    const int s0 = (tt & 31) * 16;           // row-in-batch base
    int len = lengths[b]; if (len < 1) len = 1;
    const bool tile_live = (s0 < len);
    const int row_abs = (b << 9) + s0;       // absolute row base

    // stager mapping: lane -> (row l>>2, 16B at (l&3)*16 of each 64B run)
    const int srow = lane >> 2, sm = lane & 3;
    const float* hrow = hidden + (size_t)(row_abs + srow) * H_ + sm * 4;

    // ---- prefetch panels 0,1 (coalesced; starts HBM stream pre-barrier) ----
    float4 L[2][4];
    if (tile_live) {
        #pragma unroll
        for (int m = 0; m < 4; ++m) L[0][m] = *(const float4*)(hrow + m * 16);
        #pragma unroll
        for (int m = 0; m < 4; ++m) L[1][m] = *(const float4*)(hrow + 64 + m * 16);
    }

    // ---- pack W fragments from global W (L1/L2-resident) ----
    if (T < 16) bias16[T] = (T < 9) ? bias[T] : 0.0f;
    #pragma unroll
    for (int r6 = 0; r6 < 6; ++r6) {
        const int sidx = T + 256 * r6;       // 0..1535
        const int k8 = sidx >> 4, c = sidx & 15;
        unsigned w0 = 0, w1 = 0, w2 = 0, w3 = 0;
        if (c < 9) {
            const float* wp = W + (size_t)(k8 * 8) * 9 + c;
            w0 = pack_bf16(wp[0],  wp[9]);
            w1 = pack_bf16(wp[18], wp[27]);
            w2 = pack_bf16(wp[36], wp[45]);
            w3 = pack_bf16(wp[54], wp[63]);
        }
        uint4 v = { w0, w1, w2, w3 };
        *(uint4*)&Wl[sidx * 4] = v;
    }
    __syncthreads();

    if (!tile_live) return;

    unsigned* buf0 = &hbuf[wv][0][0];
    unsigned* buf1 = &hbuf[wv][1][0];
    const int woff = srow * 36 + sm * 2;     // u32 write offset (+ m*8)
    const int rdoff = col * 36 + q * 4;      // u32 read offset (+ s*16)

    // write panel 0
    #pragma unroll
    for (int m = 0; m < 4; ++m) {
        uint2 u = { pack_bf16(L[0][m].x, L[0][m].y),
                    pack_bf16(L[0][m].z, L[0][m].w) };
        *(uint2_a*)(buf0 + woff + m * 8) = u;
    }

    const float4 bias4 = *(const float4*)(bias16 + q * 4);
    f32x4 acc = { 0.0f, 0.0f, 0.0f, 0.0f };

    #pragma unroll
    for (int p = 0; p < 12; ++p) {
        unsigned* cbuf = (p & 1) ? buf1 : buf0;
        unsigned* nbuf = (p & 1) ? buf0 : buf1;

        // prefetch panel p+2 into L[p&1] (its panel p already in LDS)
        if (p + 2 < 12) {
            #pragma unroll
            for (int m = 0; m < 4; ++m)
                L[p & 1][m] = *(const float4*)(hrow + (p + 2) * 64 + m * 16);
        }

        // consume panel p: 2 MFMA steps
        #pragma unroll
        for (int s = 0; s < 2; ++s) {
            const bf16x8 bu = *(const bf16x8_a*)(cbuf + rdoff + s * 16);
            const uint4 a4 =
                *(const uint4*)&Wl[(((p * 2 + s) * 4 + q) * 16 + col) * 4];
            union { unsigned u[4]; bf16x8 v; } au;
            au.u[0] = a4.x; au.u[1] = a4.y; au.u[2] = a4.z; au.u[3] = a4.w;
            acc = __builtin_amdgcn_mfma_f32_16x16x32_bf16(au.v, bu, acc, 0, 0, 0);
        }

        // write panel p+1
        if (p + 1 < 12) {
            #pragma unroll
            for (int m = 0; m < 4; ++m) {
                uint2 u = { pack_bf16(L[(p + 1) & 1][m].x, L[(p + 1) & 1][m].y),
                            pack_bf16(L[(p + 1) & 1][m].z, L[(p + 1) & 1][m].w) };
                *(uint2_a*)(nbuf + woff + m * 8) = u;
            }
        }
    }

    const int srow_out = s0 + col;
    if (srow_out < len) {
        float4 o = { acc[0] + bias4.x, acc[1] + bias4.y,
                     acc[2] + bias4.z, acc[3] + bias4.w };
        *(float4*)(em + (size_t)((b << 9) + srow_out) * EMP + q * 4) = o;
    }
}

// ---------------------------------------------------------------------------
// Kernel B (fused CRF): one block per batch, 384 threads.  (unchanged r20)
//  phase 0: Pl=exp(trans) -> LDS; eem=exp(em) -> LDS for t<len only.
//  phase 1: T<288: build 32 chunk transfer matrices (1 chunk/thread, row i);
//           T>=320: gold-path numerator.
//  phase 2: binary tree product of the 32 matrices (5 levels, adaptive
//           rescale, logs in LDS), then thread 0 applies alpha0 and end_t.
// ---------------------------------------------------------------------------
__global__ __launch_bounds__(384, 1) void crf_kernel(
    const float* __restrict__ em, const int* __restrict__ labels,
    const int* __restrict__ lengths, const float* __restrict__ start_t,
    const float* __restrict__ trans, const float* __restrict__ end_t,
    float* __restrict__ out)
{
    __shared__ float eem[6288];              // staggered exp(em) rows, 24.6 KiB
    __shared__ float Pl[112];                // exp(trans), rows padded to 12
    __shared__ float Cs[NCHUNK * CPAD];      // chunk matrices, 11 KiB
    __shared__ float Cs2[16 * CPAD];         // tree ping-pong, 5.5 KiB
    __shared__ float rmx_s[16 * 12];
    __shared__ float lgA[32], lgB[16];
    const int T = threadIdx.x;
    const int b = blockIdx.x;
    int len = lengths[b]; if (len < 1) len = 1;

    // ---- phase 0: shared tables ----
    if (T < 81) {
        const int k = T / 9, j = T - 9 * k;
        Pl[k * 12 + j] = __expf(trans[T]);
    }
    #pragma unroll
    for (int r = 0; r < 2; ++r) {
        const int t = T + 384 * r;
        if (t < len) {                       // rows >= len are never used
            const int o = eoff(t);
            const float4* p = (const float4*)(em + (size_t)((b << 9) + t) * EMP);
            float4 v0 = p[0], v1 = p[1], v2 = p[2];
            float4 w0 = { __expf(v0.x), __expf(v0.y), __expf(v0.z), __expf(v0.w) };
            float4 w1 = { __expf(v1.x), __expf(v1.y), __expf(v1.z), __expf(v1.w) };
            *(float4*)(eem + o) = w0;
            *(float4*)(eem + o + 4) = w1;
            eem[o + 8] = __expf(v2.x);
        }
    }
    if (T < 32) lgA[T] = 0.0f;
    __syncthreads();

    // ---- phase 1 ----
    if (T < 288) {
        const int c = T / 9;                 // 0..31, one chunk per thread
        const int i = T - 9 * c;
        float A[9];
        #pragma unroll
        for (int j = 0; j < 9; ++j) A[j] = (i == j) ? 1.0f : 0.0f;
        const int t0 = CH * c + 1;

        #pragma unroll 1
        for (int s = 0; s < CH; ++s) {
            const int t = t0 + s;
            const int o = eoff(t);
            float4 e0 = *(const float4*)(eem + o);
            float4 e1 = *(const float4*)(eem + o + 4);
            const float e8 = eem[o + 8];
            const float e[9] = { e0.x, e0.y, e0.z, e0.w,
                                 e1.x, e1.y, e1.z, e1.w, e8 };

            float an[9];
            #pragma unroll
            for (int j = 0; j < 9; ++j) an[j] = 0.0f;
            #pragma unroll
            for (int k = 0; k < 9; ++k) {
                float4 p0 = *(const float4*)(Pl + k * 12);
                float4 p1 = *(const float4*)(Pl + k * 12 + 4);
                const float p8 = Pl[k * 12 + 8];
                const float pr[9] = { p0.x, p0.y, p0.z, p0.w,
                                      p1.x, p1.y, p1.z, p1.w, p8 };
                const float ak = A[k];
                #pragma unroll
                for (int j = 0; j < 9; ++j)
                    an[j] = fmaf(ak, pr[j], an[j]);
            }
            const bool live = (t < len);
            #pragma unroll
            for (int j = 0; j < 9; ++j)
                A[j] = live ? an[j] * e[j] : A[j];
            if (s == 7) {                    // exact 2^-40; constant added at end
                #pragma unroll
                for (int j = 0; j < 9; ++j) A[j] *= 0x1p-40f;
            }
        }
        #pragma unroll
        for (int j = 0; j < 9; ++j) Cs[c * CPAD + i * 9 + j] = A[j];
    } else if (T >= 320) {
        // ---- numerator ----
        const int lane = T - 320;
        const int* lab = labels + (size_t)b * S_;
        float part = 0.0f;
        for (int t = 1 + lane; t < len; t += 64) {
            const int tp = lab[t - 1], tc = lab[t];
            part += trans[tp * 9 + tc] + em[(size_t)((b << 9) + t) * EMP + tc];
        }
        #pragma unroll
        for (int off = 32; off >= 1; off >>= 1) part += __shfl_xor(part, off, 64);
        if (lane == 0) {
            const int l0 = lab[0], le = lab[len - 1];
            const float num = start_t[l0] + em[(size_t)(b << 9) * EMP + l0]
                            + part + end_t[le];
            atomicAdd(out, -num);
        }
    }
    __syncthreads();

    // ---- phase 2a: binary tree product of 32 chunk matrices (5 levels) ----
    float* src = Cs;  float* dst = Cs2;
    float* ls  = lgA; float* ld  = lgB;
    int nn = 16;                             // output nodes this level
    #pragma unroll 1
    for (int lvl = 0; lvl < 5; ++lvl) {
        const int n = T / 9, i = T - 9 * n;
        float row[9];
        if (T < nn * 9) {
            const float* Am = src + (2 * n) * CPAD;
            const float* Bm = src + (2 * n + 1) * CPAD;
            float a[9];
            #pragma unroll
            for (int k = 0; k < 9; ++k) a[k] = Am[i * 9 + k];
            #pragma unroll
            for (int j = 0; j < 9; ++j) row[j] = 0.0f;
            #pragma unroll
            for (int k = 0; k < 9; ++k) {
                const float ak = a[k];
                #pragma unroll
                for (int j = 0; j < 9; ++j)
                    row[j] = fmaf(ak, Bm[k * 9 + j], row[j]);
            }
            float rmx = row[0];
            #pragma unroll
            for (int j = 1; j < 9; ++j) rmx = fmaxf(rmx, row[j]);
            rmx_s[n * 12 + i] = rmx;
        }
        __syncthreads();
        if (T < nn * 9) {
            float mx = rmx_s[n * 12];
            #pragma unroll
            for (int k = 1; k < 9; ++k) mx = fmaxf(mx, rmx_s[n * 12 + k]);
            const float inv = 1.0f / mx;
            #pragma unroll
            for (int j = 0; j < 9; ++j) dst[n * CPAD + i * 9 + j] = row[j] * inv;
            if (i == 0) ld[n] = ls[2 * n] + ls[2 * n + 1] + __logf(mx);
        }
        __syncthreads();
        float* t1 = src; src = dst; dst = t1;
        float* t2 = ls;  ls = ld;  ld = t2;
        nn >>= 1;
    }
    // src = final normalized matrix (node 0), ls[0] = accumulated log

    // ---- phase 2b: apply alpha0 and end transitions ----
    if (T == 0) {
        const float4* e0 = (const float4*)(em + (size_t)(b << 9) * EMP);
        float4 v0 = e0[0], v1 = e0[1], v2 = e0[2];
        float al[9] = { v0.x + start_t[0], v0.y + start_t[1], v0.z + start_t[2],
                        v0.w + start_t[3], v1.x + start_t[4], v1.y + start_t[5],
                        v1.z + start_t[6], v1.w + start_t[7], v2.x + start_t[8] };
        float m0 = al[0];
        #pragma unroll
        for (int j = 1; j < 9; ++j) m0 = fmaxf(m0, al[j]);
        float alpha[9];
        #pragma unroll
        for (int j = 0; j < 9; ++j) alpha[j] = __expf(al[j] - m0);

        float ev = 0.0f;
        #pragma unroll
        for (int j = 0; j < 9; ++j) {
            float s = 0.0f;
            #pragma unroll
            for (int i = 0; i < 9; ++i)
                s = fmaf(alpha[i], src[i * 9 + j], s);
            ev = fmaf(s, __expf(end_t[j]), ev);
        }
        // 32 chunks x 2^-40 scaling -> +1280*ln2 exact constant
        const float den = m0 + ls[0] + __logf(ev)
                        + 1280.0f * 0.6931471805599453f;
        atomicAdd(out, den);
    }
}

// ---------------------------------------------------------------------------
extern "C" void kernel_launch(void* const* d_in, const int* in_sizes, int n_in,
                              void* d_out, int out_size, void* d_ws, size_t ws_size,
                              hipStream_t stream)
{
    (void)in_sizes; (void)n_in; (void)out_size; (void)ws_size;
    const float* hidden  = (const float*)d_in[0];
    const float* W       = (const float*)d_in[1];
    const float* bias    = (const float*)d_in[2];
    const float* start_t = (const float*)d_in[3];
    const float* trans   = (const float*)d_in[4];
    const float* end_t   = (const float*)d_in[5];
    const int*   labels  = (const int*)d_in[6];
    const int*   lengths = (const int*)d_in[7];

    float* em  = (float*)d_ws;               // 64*512*16 floats = 2 MB
    float* out = (float*)d_out;

    emis_kernel<<<512, 256, 0, stream>>>(hidden, W, bias, lengths, em, out);
    crf_kernel<<<B_, 384, 0, stream>>>(em, labels, lengths,
                                       start_t, trans, end_t, out);
}

// Round 22
// 28.000 us; speedup vs baseline: 1.1688x; 1.0464x over previous
//
#include <hip/hip_runtime.h>

#define B_ 64
#define S_ 512
#define H_ 768
#define L_ 9
#define EMP 16                  // padded emission row stride in global (floats)
#define CH 16                   // timesteps per chunk
#define NCHUNK 32               // chunks per batch
#define CPAD 88                 // floats per chunk record in LDS (16B-aligned)

typedef __attribute__((ext_vector_type(8))) short bf16x8;
typedef __attribute__((ext_vector_type(4))) float f32x4;
typedef bf16x8 __attribute__((may_alias)) bf16x8_a;
typedef uint2  __attribute__((may_alias)) uint2_a;

// eem LDS offset for timestep t: 16B-aligned, bank-staggered per 16-row group
__device__ __forceinline__ int eoff(int t) { return t * 12 + (t >> 4) * 4; }

// pack two fp32 -> one u32 of two bf16 (round-to-nearest via +0x8000)
__device__ __forceinline__ unsigned pack_bf16(float lo, float hi) {
    unsigned a = __float_as_uint(lo) + 0x8000u;
    unsigned b = __float_as_uint(hi) + 0x8000u;
    return __builtin_amdgcn_perm(b, a, 0x07060302);  // {b.b23, a.b23}
}

// ---------------------------------------------------------------------------
// Kernel A (MFMA, coalesced-staged, 1 block/CU self-balanced): em = hidden@W+b.
// 256 blocks x 512 threads (8 waves): exactly one block per CU -> zero
// block-pairing variance. Wave w of block g takes tile
//   batch = (g>>5) + 8w,  pos = (g&31) ^ ((w&1)<<4)        (bijective)
// so each block samples 8 batches at complementary positions: per-block live
// count concentrates at the ~4.1 mean (r21's mapping gave all 4 tiles the
// same pos AND paired same-pos blocks on one CU -> worst-CU ~2x mean).
// Hidden stream: coalesced global->reg->bf16 pack->per-wave LDS panel
// (double-buffered, 144B rows)->ds_read_b128 fragments; no K-loop barriers.
// Also zeroes out[0] (runs before the CRF kernel in stream order).
// ---------------------------------------------------------------------------
__global__ __launch_bounds__(512) void emis_kernel(
    const float* __restrict__ hidden, const float* __restrict__ W,
    const float* __restrict__ bias, const int* __restrict__ lengths,
    float* __restrict__ em, float* __restrict__ out)
{
    __shared__ unsigned Wl[96 * 16 * 4];     // bf16x8 frags [k8][col] (24 KB)
    __shared__ float bias16[16];
    __shared__ unsigned hbuf[8][2][16 * 36]; // per-wave panels: 16 rows x 144B

    const int T = threadIdx.x;
    if (blockIdx.x == 0 && T == 0) out[0] = 0.0f;

    const int g = blockIdx.x;                // 0..255

    const int wv = T >> 6, lane = T & 63;
    const int q = lane >> 4, col = lane & 15;

    const int b   = (g >> 5) + 8 * wv;       // batch 0..63
    const int pos = (g & 31) ^ ((wv & 1) << 4);
    const int s0  = pos * 16;                // row-in-batch base
    int len = lengths[b]; if (len < 1) len = 1;
    const bool tile_live = (s0 < len);
    const int row_abs = (b << 9) + s0;       // absolute row base

    // stager mapping: lane -> (row l>>2, 16B at (l&3)*16 of each 64B run)
    const int srow = lane >> 2, sm = lane & 3;
    const float* hrow = hidden + (size_t)(row_abs + srow) * H_ + sm * 4;

    // ---- prefetch panels 0,1 (coalesced; starts HBM stream pre-barrier) ----
    float4 L[2][4];
    if (tile_live) {
        #pragma unroll
        for (int m = 0; m < 4; ++m) L[0][m] = *(const float4*)(hrow + m * 16);
        #pragma unroll
        for (int m = 0; m < 4; ++m) L[1][m] = *(const float4*)(hrow + 64 + m * 16);
    }

    // ---- pack W fragments from global W (L1/L2-resident) ----
    if (T < 16) bias16[T] = (T < 9) ? bias[T] : 0.0f;
    #pragma unroll
    for (int r3 = 0; r3 < 3; ++r3) {
        const int sidx = T + 512 * r3;       // 0..1535
        const int k8 = sidx >> 4, c = sidx & 15;
        unsigned w0 = 0, w1 = 0, w2 = 0, w3 = 0;
        if (c < 9) {
            const float* wp = W + (size_t)(k8 * 8) * 9 + c;
            w0 = pack_bf16(wp[0],  wp[9]);
            w1 = pack_bf16(wp[18], wp[27]);
            w2 = pack_bf16(wp[36], wp[45]);
            w3 = pack_bf16(wp[54], wp[63]);
        }
        uint4 v = { w0, w1, w2, w3 };
        *(uint4*)&Wl[sidx * 4] = v;
    }
    __syncthreads();

    if (!tile_live) return;

    unsigned* buf0 = &hbuf[wv][0][0];
    unsigned* buf1 = &hbuf[wv][1][0];
    const int woff = srow * 36 + sm * 2;     // u32 write offset (+ m*8)
    const int rdoff = col * 36 + q * 4;      // u32 read offset (+ s*16)

    // write panel 0
    #pragma unroll
    for (int m = 0; m < 4; ++m) {
        uint2 u = { pack_bf16(L[0][m].x, L[0][m].y),
                    pack_bf16(L[0][m].z, L[0][m].w) };
        *(uint2_a*)(buf0 + woff + m * 8) = u;
    }

    const float4 bias4 = *(const float4*)(bias16 + q * 4);
    f32x4 acc = { 0.0f, 0.0f, 0.0f, 0.0f };

    #pragma unroll
    for (int p = 0; p < 12; ++p) {
        unsigned* cbuf = (p & 1) ? buf1 : buf0;
        unsigned* nbuf = (p & 1) ? buf0 : buf1;

        // prefetch panel p+2 into L[p&1] (its panel p already in LDS)
        if (p + 2 < 12) {
            #pragma unroll
            for (int m = 0; m < 4; ++m)
                L[p & 1][m] = *(const float4*)(hrow + (p + 2) * 64 + m * 16);
        }

        // consume panel p: 2 MFMA steps
        #pragma unroll
        for (int s = 0; s < 2; ++s) {
            const bf16x8 bu = *(const bf16x8_a*)(cbuf + rdoff + s * 16);
            const uint4 a4 =
                *(const uint4*)&Wl[(((p * 2 + s) * 4 + q) * 16 + col) * 4];
            union { unsigned u[4]; bf16x8 v; } au;
            au.u[0] = a4.x; au.u[1] = a4.y; au.u[2] = a4.z; au.u[3] = a4.w;
            acc = __builtin_amdgcn_mfma_f32_16x16x32_bf16(au.v, bu, acc, 0, 0, 0);
        }

        // write panel p+1
        if (p + 1 < 12) {
            #pragma unroll
            for (int m = 0; m < 4; ++m) {
                uint2 u = { pack_bf16(L[(p + 1) & 1][m].x, L[(p + 1) & 1][m].y),
                            pack_bf16(L[(p + 1) & 1][m].z, L[(p + 1) & 1][m].w) };
                *(uint2_a*)(nbuf + woff + m * 8) = u;
            }
        }
    }

    const int srow_out = s0 + col;
    if (srow_out < len) {
        float4 o = { acc[0] + bias4.x, acc[1] + bias4.y,
                     acc[2] + bias4.z, acc[3] + bias4.w };
        *(float4*)(em + (size_t)((b << 9) + srow_out) * EMP + q * 4) = o;
    }
}

// ---------------------------------------------------------------------------
// Kernel B (fused CRF): one block per batch, 384 threads.  (unchanged r21)
//  phase 0: Pl=exp(trans) -> LDS; eem=exp(em) -> LDS for t<len only.
//  phase 1: T<288: build 32 chunk transfer matrices (1 chunk/thread, row i);
//           T>=320: gold-path numerator.
//  phase 2: binary tree product of the 32 matrices (5 levels, adaptive
//           rescale, logs in LDS), then thread 0 applies alpha0 and end_t.
// ---------------------------------------------------------------------------
__global__ __launch_bounds__(384, 1) void crf_kernel(
    const float* __restrict__ em, const int* __restrict__ labels,
    const int* __restrict__ lengths, const float* __restrict__ start_t,
    const float* __restrict__ trans, const float* __restrict__ end_t,
    float* __restrict__ out)
{
    __shared__ float eem[6288];              // staggered exp(em) rows, 24.6 KiB
    __shared__ float Pl[112];                // exp(trans), rows padded to 12
    __shared__ float Cs[NCHUNK * CPAD];      // chunk matrices, 11 KiB
    __shared__ float Cs2[16 * CPAD];         // tree ping-pong, 5.5 KiB
    __shared__ float rmx_s[16 * 12];
    __shared__ float lgA[32], lgB[16];
    const int T = threadIdx.x;
    const int b = blockIdx.x;
    int len = lengths[b]; if (len < 1) len = 1;

    // ---- phase 0: shared tables ----
    if (T < 81) {
        const int k = T / 9, j = T - 9 * k;
        Pl[k * 12 + j] = __expf(trans[T]);
    }
    #pragma unroll
    for (int r = 0; r < 2; ++r) {
        const int t = T + 384 * r;
        if (t < len) {                       // rows >= len are never used
            const int o = eoff(t);
            const float4* p = (const float4*)(em + (size_t)((b << 9) + t) * EMP);
            float4 v0 = p[0], v1 = p[1], v2 = p[2];
            float4 w0 = { __expf(v0.x), __expf(v0.y), __expf(v0.z), __expf(v0.w) };
            float4 w1 = { __expf(v1.x), __expf(v1.y), __expf(v1.z), __expf(v1.w) };
            *(float4*)(eem + o) = w0;
            *(float4*)(eem + o + 4) = w1;
            eem[o + 8] = __expf(v2.x);
        }
    }
    if (T < 32) lgA[T] = 0.0f;
    __syncthreads();

    // ---- phase 1 ----
    if (T < 288) {
        const int c = T / 9;                 // 0..31, one chunk per thread
        const int i = T - 9 * c;
        float A[9];
        #pragma unroll
        for (int j = 0; j < 9; ++j) A[j] = (i == j) ? 1.0f : 0.0f;
        const int t0 = CH * c + 1;

        #pragma unroll 1
        for (int s = 0; s < CH; ++s) {
            const int t = t0 + s;
            const int o = eoff(t);
            float4 e0 = *(const float4*)(eem + o);
            float4 e1 = *(const float4*)(eem + o + 4);
            const float e8 = eem[o + 8];
            const float e[9] = { e0.x, e0.y, e0.z, e0.w,
                                 e1.x, e1.y, e1.z, e1.w, e8 };

            float an[9];
            #pragma unroll
            for (int j = 0; j < 9; ++j) an[j] = 0.0f;
            #pragma unroll
            for (int k = 0; k < 9; ++k) {
                float4 p0 = *(const float4*)(Pl + k * 12);
                float4 p1 = *(const float4*)(Pl + k * 12 + 4);
                const float p8 = Pl[k * 12 + 8];
                const float pr[9] = { p0.x, p0.y, p0.z, p0.w,
                                      p1.x, p1.y, p1.z, p1.w, p8 };
                const float ak = A[k];
                #pragma unroll
                for (int j = 0; j < 9; ++j)
                    an[j] = fmaf(ak, pr[j], an[j]);
            }
            const bool live = (t < len);
            #pragma unroll
            for (int j = 0; j < 9; ++j)
                A[j] = live ? an[j] * e[j] : A[j];
            if (s == 7) {                    // exact 2^-40; constant added at end
                #pragma unroll
                for (int j = 0; j < 9; ++j) A[j] *= 0x1p-40f;
            }
        }
        #pragma unroll
        for (int j = 0; j < 9; ++j) Cs[c * CPAD + i * 9 + j] = A[j];
    } else if (T >= 320) {
        // ---- numerator ----
        const int lane = T - 320;
        const int* lab = labels + (size_t)b * S_;
        float part = 0.0f;
        for (int t = 1 + lane; t < len; t += 64) {
            const int tp = lab[t - 1], tc = lab[t];
            part += trans[tp * 9 + tc] + em[(size_t)((b << 9) + t) * EMP + tc];
        }
        #pragma unroll
        for (int off = 32; off >= 1; off >>= 1) part += __shfl_xor(part, off, 64);
        if (lane == 0) {
            const int l0 = lab[0], le = lab[len - 1];
            const float num = start_t[l0] + em[(size_t)(b << 9) * EMP + l0]
                            + part + end_t[le];
            atomicAdd(out, -num);
        }
    }
    __syncthreads();

    // ---- phase 2a: binary tree product of 32 chunk matrices (5 levels) ----
    float* src = Cs;  float* dst = Cs2;
    float* ls  = lgA; float* ld  = lgB;
    int nn = 16;                             // output nodes this level
    #pragma unroll 1
    for (int lvl = 0; lvl < 5; ++lvl) {
        const int n = T / 9, i = T - 9 * n;
        float row[9];
        if (T < nn * 9) {
            const float* Am = src + (2 * n) * CPAD;
            const float* Bm = src + (2 * n + 1) * CPAD;
            float a[9];
            #pragma unroll
            for (int k = 0; k < 9; ++k) a[k] = Am[i * 9 + k];
            #pragma unroll
            for (int j = 0; j < 9; ++j) row[j] = 0.0f;
            #pragma unroll
            for (int k = 0; k < 9; ++k) {
                const float ak = a[k];
                #pragma unroll
                for (int j = 0; j < 9; ++j)
                    row[j] = fmaf(ak, Bm[k * 9 + j], row[j]);
            }
            float rmx = row[0];
            #pragma unroll
            for (int j = 1; j < 9; ++j) rmx = fmaxf(rmx, row[j]);
            rmx_s[n * 12 + i] = rmx;
        }
        __syncthreads();
        if (T < nn * 9) {
            float mx = rmx_s[n * 12];
            #pragma unroll
            for (int k = 1; k < 9; ++k) mx = fmaxf(mx, rmx_s[n * 12 + k]);
            const float inv = 1.0f / mx;
            #pragma unroll
            for (int j = 0; j < 9; ++j) dst[n * CPAD + i * 9 + j] = row[j] * inv;
            if (i == 0) ld[n] = ls[2 * n] + ls[2 * n + 1] + __logf(mx);
        }
        __syncthreads();
        float* t1 = src; src = dst; dst = t1;
        float* t2 = ls;  ls = ld;  ld = t2;
        nn >>= 1;
    }
    // src = final normalized matrix (node 0), ls[0] = accumulated log

    // ---- phase 2b: apply alpha0 and end transitions ----
    if (T == 0) {
        const float4* e0 = (const float4*)(em + (size_t)(b << 9) * EMP);
        float4 v0 = e0[0], v1 = e0[1], v2 = e0[2];
        float al[9] = { v0.x + start_t[0], v0.y + start_t[1], v0.z + start_t[2],
                        v0.w + start_t[3], v1.x + start_t[4], v1.y + start_t[5],
                        v1.z + start_t[6], v1.w + start_t[7], v2.x + start_t[8] };
        float m0 = al[0];
        #pragma unroll
        for (int j = 1; j < 9; ++j) m0 = fmaxf(m0, al[j]);
        float alpha[9];
        #pragma unroll
        for (int j = 0; j < 9; ++j) alpha[j] = __expf(al[j] - m0);

        float ev = 0.0f;
        #pragma unroll
        for (int j = 0; j < 9; ++j) {
            float s = 0.0f;
            #pragma unroll
            for (int i = 0; i < 9; ++i)
                s = fmaf(alpha[i], src[i * 9 + j], s);
            ev = fmaf(s, __expf(end_t[j]), ev);
        }
        // 32 chunks x 2^-40 scaling -> +1280*ln2 exact constant
        const float den = m0 + ls[0] + __logf(ev)
                        + 1280.0f * 0.6931471805599453f;
        atomicAdd(out, den);
    }
}

// ---------------------------------------------------------------------------
extern "C" void kernel_launch(void* const* d_in, const int* in_sizes, int n_in,
                              void* d_out, int out_size, void* d_ws, size_t ws_size,
                              hipStream_t stream)
{
    (void)in_sizes; (void)n_in; (void)out_size; (void)ws_size;
    const float* hidden  = (const float*)d_in[0];
    const float* W       = (const float*)d_in[1];
    const float* bias    = (const float*)d_in[2];
    const float* start_t = (const float*)d_in[3];
    const float* trans   = (const float*)d_in[4];
    const float* end_t   = (const float*)d_in[5];
    const int*   labels  = (const int*)d_in[6];
    const int*   lengths = (const int*)d_in[7];

    float* em  = (float*)d_ws;               // 64*512*16 floats = 2 MB
    float* out = (float*)d_out;

    emis_kernel<<<256, 512, 0, stream>>>(hidden, W, bias, lengths, em, out);
    crf_kernel<<<B_, 384, 0, stream>>>(em, labels, lengths,
                                       start_t, trans, end_t, out);
}

// Round 23
// 27.878 us; speedup vs baseline: 1.1739x; 1.0044x over previous
//
#include <hip/hip_runtime.h>

#define B_ 64
#define S_ 512
#define H_ 768
#define L_ 9
#define EMP 16                  // padded emission row stride in global (floats)
#define CH 16                   // timesteps per chunk
#define NCHUNK 32               // chunks per batch
#define CPAD 88                 // floats per chunk record in LDS (16B-aligned)

typedef __attribute__((ext_vector_type(8))) short bf16x8;
typedef __attribute__((ext_vector_type(4))) float f32x4;
typedef bf16x8 __attribute__((may_alias)) bf16x8_a;
typedef uint2  __attribute__((may_alias)) uint2_a;

// eem LDS offset for timestep t: 16B-aligned, bank-staggered per 16-row group
__device__ __forceinline__ int eoff(int t) { return t * 12 + (t >> 4) * 4; }

// pack two fp32 -> one u32 of two bf16 (round-to-nearest via +0x8000)
__device__ __forceinline__ unsigned pack_bf16(float lo, float hi) {
    unsigned a = __float_as_uint(lo) + 0x8000u;
    unsigned b = __float_as_uint(hi) + 0x8000u;
    return __builtin_amdgcn_perm(b, a, 0x07060302);  // {b.b23, a.b23}
}

// ---------------------------------------------------------------------------
// Kernel A (MFMA, coalesced-staged, mean-exact balanced): em = hidden@W+b.
// 256 blocks x 512 threads (8 waves), one block per CU. Wave w of block g:
//   pos   = 4w + ((g>>6) ^ (w&3))      (position multiset sum = 124 for ALL
//                                       blocks -> E[live]=4.125 everywhere)
//   batch = (g + 9w) & 63              (8 spread batches, decorrelated sets)
// Bijective over all 2048 tiles: w=pos>>2, g>>6=(pos&3)^(w&3), g&63=(b-9w)%64.
// r22's mapping had a 2.3x deterministic spread in E[live] across blocks
// (positions {p, p^16} -> E[live] 2.6..6.0) and 32 blocks shared a batch set.
// Hidden stream: coalesced global->reg->bf16 pack->per-wave LDS panel
// (double-buffered, 144B rows)->ds_read_b128 fragments; no K-loop barriers.
// Also zeroes out[0] (runs before the CRF kernel in stream order).
// ---------------------------------------------------------------------------
__global__ __launch_bounds__(512) void emis_kernel(
    const float* __restrict__ hidden, const float* __restrict__ W,
    const float* __restrict__ bias, const int* __restrict__ lengths,
    float* __restrict__ em, float* __restrict__ out)
{
    __shared__ unsigned Wl[96 * 16 * 4];     // bf16x8 frags [k8][col] (24 KB)
    __shared__ float bias16[16];
    __shared__ unsigned hbuf[8][2][16 * 36]; // per-wave panels: 16 rows x 144B

    const int T = threadIdx.x;
    if (blockIdx.x == 0 && T == 0) out[0] = 0.0f;

    const int g = blockIdx.x;                // 0..255

    const int wv = T >> 6, lane = T & 63;
    const int q = lane >> 4, col = lane & 15;

    const int b   = (g + 9 * wv) & 63;               // batch 0..63
    const int pos = 4 * wv + ((g >> 6) ^ (wv & 3));  // 0..31
    const int s0  = pos * 16;                // row-in-batch base
    int len = lengths[b]; if (len < 1) len = 1;
    const bool tile_live = (s0 < len);
    const int row_abs = (b << 9) + s0;       // absolute row base

    // stager mapping: lane -> (row l>>2, 16B at (l&3)*16 of each 64B run)
    const int srow = lane >> 2, sm = lane & 3;
    const float* hrow = hidden + (size_t)(row_abs + srow) * H_ + sm * 4;

    // ---- prefetch panels 0,1 (coalesced; starts HBM stream pre-barrier) ----
    float4 L[2][4];
    if (tile_live) {
        #pragma unroll
        for (int m = 0; m < 4; ++m) L[0][m] = *(const float4*)(hrow + m * 16);
        #pragma unroll
        for (int m = 0; m < 4; ++m) L[1][m] = *(const float4*)(hrow + 64 + m * 16);
    }

    // ---- pack W fragments from global W (L1/L2-resident) ----
    if (T < 16) bias16[T] = (T < 9) ? bias[T] : 0.0f;
    #pragma unroll
    for (int r3 = 0; r3 < 3; ++r3) {
        const int sidx = T + 512 * r3;       // 0..1535
        const int k8 = sidx >> 4, c = sidx & 15;
        unsigned w0 = 0, w1 = 0, w2 = 0, w3 = 0;
        if (c < 9) {
            const float* wp = W + (size_t)(k8 * 8) * 9 + c;
            w0 = pack_bf16(wp[0],  wp[9]);
            w1 = pack_bf16(wp[18], wp[27]);
            w2 = pack_bf16(wp[36], wp[45]);
            w3 = pack_bf16(wp[54], wp[63]);
        }
        uint4 v = { w0, w1, w2, w3 };
        *(uint4*)&Wl[sidx * 4] = v;
    }
    __syncthreads();

    if (!tile_live) return;

    unsigned* buf0 = &hbuf[wv][0][0];
    unsigned* buf1 = &hbuf[wv][1][0];
    const int woff = srow * 36 + sm * 2;     // u32 write offset (+ m*8)
    const int rdoff = col * 36 + q * 4;      // u32 read offset (+ s*16)

    // write panel 0
    #pragma unroll
    for (int m = 0; m < 4; ++m) {
        uint2 u = { pack_bf16(L[0][m].x, L[0][m].y),
                    pack_bf16(L[0][m].z, L[0][m].w) };
        *(uint2_a*)(buf0 + woff + m * 8) = u;
    }

    const float4 bias4 = *(const float4*)(bias16 + q * 4);
    f32x4 acc = { 0.0f, 0.0f, 0.0f, 0.0f };

    #pragma unroll
    for (int p = 0; p < 12; ++p) {
        unsigned* cbuf = (p & 1) ? buf1 : buf0;
        unsigned* nbuf = (p & 1) ? buf0 : buf1;

        // prefetch panel p+2 into L[p&1] (its panel p already in LDS)
        if (p + 2 < 12) {
            #pragma unroll
            for (int m = 0; m < 4; ++m)
                L[p & 1][m] = *(const float4*)(hrow + (p + 2) * 64 + m * 16);
        }

        // consume panel p: 2 MFMA steps
        #pragma unroll
        for (int s = 0; s < 2; ++s) {
            const bf16x8 bu = *(const bf16x8_a*)(cbuf + rdoff + s * 16);
            const uint4 a4 =
                *(const uint4*)&Wl[(((p * 2 + s) * 4 + q) * 16 + col) * 4];
            union { unsigned u[4]; bf16x8 v; } au;
            au.u[0] = a4.x; au.u[1] = a4.y; au.u[2] = a4.z; au.u[3] = a4.w;
            acc = __builtin_amdgcn_mfma_f32_16x16x32_bf16(au.v, bu, acc, 0, 0, 0);
        }

        // write panel p+1
        if (p + 1 < 12) {
            #pragma unroll
            for (int m = 0; m < 4; ++m) {
                uint2 u = { pack_bf16(L[(p + 1) & 1][m].x, L[(p + 1) & 1][m].y),
                            pack_bf16(L[(p + 1) & 1][m].z, L[(p + 1) & 1][m].w) };
                *(uint2_a*)(nbuf + woff + m * 8) = u;
            }
        }
    }

    const int srow_out = s0 + col;
    if (srow_out < len) {
        float4 o = { acc[0] + bias4.x, acc[1] + bias4.y,
                     acc[2] + bias4.z, acc[3] + bias4.w };
        *(float4*)(em + (size_t)((b << 9) + srow_out) * EMP + q * 4) = o;
    }
}

// ---------------------------------------------------------------------------
// Kernel B (fused CRF): one block per batch, 384 threads.  (unchanged r22)
//  phase 0: Pl=exp(trans) -> LDS; eem=exp(em) -> LDS for t<len only.
//  phase 1: T<288: build 32 chunk transfer matrices (1 chunk/thread, row i);
//           T>=320: gold-path numerator.
//  phase 2: binary tree product of the 32 matrices (5 levels, adaptive
//           rescale, logs in LDS), then thread 0 applies alpha0 and end_t.
// ---------------------------------------------------------------------------
__global__ __launch_bounds__(384, 1) void crf_kernel(
    const float* __restrict__ em, const int* __restrict__ labels,
    const int* __restrict__ lengths, const float* __restrict__ start_t,
    const float* __restrict__ trans, const float* __restrict__ end_t,
    float* __restrict__ out)
{
    __shared__ float eem[6288];              // staggered exp(em) rows, 24.6 KiB
    __shared__ float Pl[112];                // exp(trans), rows padded to 12
    __shared__ float Cs[NCHUNK * CPAD];      // chunk matrices, 11 KiB
    __shared__ float Cs2[16 * CPAD];         // tree ping-pong, 5.5 KiB
    __shared__ float rmx_s[16 * 12];
    __shared__ float lgA[32], lgB[16];
    const int T = threadIdx.x;
    const int b = blockIdx.x;
    int len = lengths[b]; if (len < 1) len = 1;

    // ---- phase 0: shared tables ----
    if (T < 81) {
        const int k = T / 9, j = T - 9 * k;
        Pl[k * 12 + j] = __expf(trans[T]);
    }
    #pragma unroll
    for (int r = 0; r < 2; ++r) {
        const int t = T + 384 * r;
        if (t < len) {                       // rows >= len are never used
            const int o = eoff(t);
            const float4* p = (const float4*)(em + (size_t)((b << 9) + t) * EMP);
            float4 v0 = p[0], v1 = p[1], v2 = p[2];
            float4 w0 = { __expf(v0.x), __expf(v0.y), __expf(v0.z), __expf(v0.w) };
            float4 w1 = { __expf(v1.x), __expf(v1.y), __expf(v1.z), __expf(v1.w) };
            *(float4*)(eem + o) = w0;
            *(float4*)(eem + o + 4) = w1;
            eem[o + 8] = __expf(v2.x);
        }
    }
    if (T < 32) lgA[T] = 0.0f;
    __syncthreads();

    // ---- phase 1 ----
    if (T < 288) {
        const int c = T / 9;                 // 0..31, one chunk per thread
        const int i = T - 9 * c;
        float A[9];
        #pragma unroll
        for (int j = 0; j < 9; ++j) A[j] = (i == j) ? 1.0f : 0.0f;
        const int t0 = CH * c + 1;

        #pragma unroll 1
        for (int s = 0; s < CH; ++s) {
            const int t = t0 + s;
            const int o = eoff(t);
            float4 e0 = *(const float4*)(eem + o);
            float4 e1 = *(const float4*)(eem + o + 4);
            const float e8 = eem[o + 8];
            const float e[9] = { e0.x, e0.y, e0.z, e0.w,
                                 e1.x, e1.y, e1.z, e1.w, e8 };

            float an[9];
            #pragma unroll
            for (int j = 0; j < 9; ++j) an[j] = 0.0f;
            #pragma unroll
            for (int k = 0; k < 9; ++k) {
                float4 p0 = *(const float4*)(Pl + k * 12);
                float4 p1 = *(const float4*)(Pl + k * 12 + 4);
                const float p8 = Pl[k * 12 + 8];
                const float pr[9] = { p0.x, p0.y, p0.z, p0.w,
                                      p1.x, p1.y, p1.z, p1.w, p8 };
                const float ak = A[k];
                #pragma unroll
                for (int j = 0; j < 9; ++j)
                    an[j] = fmaf(ak, pr[j], an[j]);
            }
            const bool live = (t < len);
            #pragma unroll
            for (int j = 0; j < 9; ++j)
                A[j] = live ? an[j] * e[j] : A[j];
            if (s == 7) {                    // exact 2^-40; constant added at end
                #pragma unroll
                for (int j = 0; j < 9; ++j) A[j] *= 0x1p-40f;
            }
        }
        #pragma unroll
        for (int j = 0; j < 9; ++j) Cs[c * CPAD + i * 9 + j] = A[j];
    } else if (T >= 320) {
        // ---- numerator ----
        const int lane = T - 320;
        const int* lab = labels + (size_t)b * S_;
        float part = 0.0f;
        for (int t = 1 + lane; t < len; t += 64) {
            const int tp = lab[t - 1], tc = lab[t];
            part += trans[tp * 9 + tc] + em[(size_t)((b << 9) + t) * EMP + tc];
        }
        #pragma unroll
        for (int off = 32; off >= 1; off >>= 1) part += __shfl_xor(part, off, 64);
        if (lane == 0) {
            const int l0 = lab[0], le = lab[len - 1];
            const float num = start_t[l0] + em[(size_t)(b << 9) * EMP + l0]
                            + part + end_t[le];
            atomicAdd(out, -num);
        }
    }
    __syncthreads();

    // ---- phase 2a: binary tree product of 32 chunk matrices (5 levels) ----
    float* src = Cs;  float* dst = Cs2;
    float* ls  = lgA; float* ld  = lgB;
    int nn = 16;                             // output nodes this level
    #pragma unroll 1
    for (int lvl = 0; lvl < 5; ++lvl) {
        const int n = T / 9, i = T - 9 * n;
        float row[9];
        if (T < nn * 9) {
            const float* Am = src + (2 * n) * CPAD;
            const float* Bm = src + (2 * n + 1) * CPAD;
            float a[9];
            #pragma unroll
            for (int k = 0; k < 9; ++k) a[k] = Am[i * 9 + k];
            #pragma unroll
            for (int j = 0; j < 9; ++j) row[j] = 0.0f;
            #pragma unroll
            for (int k = 0; k < 9; ++k) {
                const float ak = a[k];
                #pragma unroll
                for (int j = 0; j < 9; ++j)
                    row[j] = fmaf(ak, Bm[k * 9 + j], row[j]);
            }
            float rmx = row[0];
            #pragma unroll
            for (int j = 1; j < 9; ++j) rmx = fmaxf(rmx, row[j]);
            rmx_s[n * 12 + i] = rmx;
        }
        __syncthreads();
        if (T < nn * 9) {
            float mx = rmx_s[n * 12];
            #pragma unroll
            for (int k = 1; k < 9; ++k) mx = fmaxf(mx, rmx_s[n * 12 + k]);
            const float inv = 1.0f / mx;
            #pragma unroll
            for (int j = 0; j < 9; ++j) dst[n * CPAD + i * 9 + j] = row[j] * inv;
            if (i == 0) ld[n] = ls[2 * n] + ls[2 * n + 1] + __logf(mx);
        }
        __syncthreads();
        float* t1 = src; src = dst; dst = t1;
        float* t2 = ls;  ls = ld;  ld = t2;
        nn >>= 1;
    }
    // src = final normalized matrix (node 0), ls[0] = accumulated log

    // ---- phase 2b: apply alpha0 and end transitions ----
    if (T == 0) {
        const float4* e0 = (const float4*)(em + (size_t)(b << 9) * EMP);
        float4 v0 = e0[0], v1 = e0[1], v2 = e0[2];
        float al[9] = { v0.x + start_t[0], v0.y + start_t[1], v0.z + start_t[2],
                        v0.w + start_t[3], v1.x + start_t[4], v1.y + start_t[5],
                        v1.z + start_t[6], v1.w + start_t[7], v2.x + start_t[8] };
        float m0 = al[0];
        #pragma unroll
        for (int j = 1; j < 9; ++j) m0 = fmaxf(m0, al[j]);
        float alpha[9];
        #pragma unroll
        for (int j = 0; j < 9; ++j) alpha[j] = __expf(al[j] - m0);

        float ev = 0.0f;
        #pragma unroll
        for (int j = 0; j < 9; ++j) {
            float s = 0.0f;
            #pragma unroll
            for (int i = 0; i < 9; ++i)
                s = fmaf(alpha[i], src[i * 9 + j], s);
            ev = fmaf(s, __expf(end_t[j]), ev);
        }
        // 32 chunks x 2^-40 scaling -> +1280*ln2 exact constant
        const float den = m0 + ls[0] + __logf(ev)
                        + 1280.0f * 0.6931471805599453f;
        atomicAdd(out, den);
    }
}

// ---------------------------------------------------------------------------
extern "C" void kernel_launch(void* const* d_in, const int* in_sizes, int n_in,
                              void* d_out, int out_size, void* d_ws, size_t ws_size,
                              hipStream_t stream)
{
    (void)in_sizes; (void)n_in; (void)out_size; (void)ws_size;
    const float* hidden  = (const float*)d_in[0];
    const float* W       = (const float*)d_in[1];
    const float* bias    = (const float*)d_in[2];
    const float* start_t = (const float*)d_in[3];
    const float* trans   = (const float*)d_in[4];
    const float* end_t   = (const float*)d_in[5];
    const int*   labels  = (const int*)d_in[6];
    const int*   lengths = (const int*)d_in[7];

    float* em  = (float*)d_ws;               // 64*512*16 floats = 2 MB
    float* out = (float*)d_out;

    emis_kernel<<<256, 512, 0, stream>>>(hidden, W, bias, lengths, em, out);
    crf_kernel<<<B_, 384, 0, stream>>>(em, labels, lengths,
                                       start_t, trans, end_t, out);
}